// Round 1
// baseline (329.497 us; speedup 1.0000x reference)
//
#include <hip/hip_runtime.h>

// Problem constants (from reference)
#define BB 32
#define HH 128
#define WW 512
#define CC 32
#define OUT_H 64
#define OUT_W 256

// One thread per output float4 (4 channels). 8 consecutive lanes = one output
// pixel (32 channels, 128 B contiguous). Total float4s = 32*64*256*8 = 4,194,304.
__global__ __launch_bounds__(256) void bilin_kernel(
    const float* __restrict__ image,
    const float* __restrict__ theta,
    float* __restrict__ out)
{
    const int gid = blockIdx.x * blockDim.x + threadIdx.x;
    const int c4 = gid & 7;          // which float4 within the 32 channels
    const int p  = gid >> 3;         // output pixel index: b*16384 + i*256 + j
    const int j  = p & (OUT_W - 1);
    const int i  = (p >> 8) & (OUT_H - 1);
    const int b  = p >> 14;

    // theta with the reference's debug hack
    float t0 = theta[b * 6 + 0];
    float t1 = theta[b * 6 + 1];
    float t2 = theta[b * 6 + 2];
    float t3 = theta[b * 6 + 3];
    float t4 = theta[b * 6 + 4];
    float t5 = theta[b * 6 + 5];
    if (b == 0) { t3 = 0.0f; t4 = 0.0f; t5 = 0.0f; }
    if (b == 1) { t0 = 0.0f; t1 = 0.0f; t2 = 0.0f; }

    // sampling grid in [-1,1]: linspace(-1,1,OUT_W)[j], linspace(-1,1,OUT_H)[i]
    const float xg = -1.0f + 2.0f * (float)j / 255.0f;
    const float yg = -1.0f + 2.0f * (float)i / 63.0f;

    const float xh = t0 * xg + t1 * yg + t2;
    const float yh = t3 * xg + t4 * yg + t5;
    const float x = 0.5f * (xh + 1.0f) * (float)WW;   // uses W, not W-1 (per ref)
    const float y = 0.5f * (yh + 1.0f) * (float)HH;

    // truncation toward zero (matches astype(int32)), then clip — weights use
    // the CLIPPED integer coords, exactly as the reference does.
    int x0 = (int)x;
    int y0 = (int)y;
    int x1 = x0 + 1;
    int y1 = y0 + 1;
    x0 = min(max(x0, 0), WW - 1);
    x1 = min(max(x1, 0), WW - 1);
    y0 = min(max(y0, 0), HH - 1);
    y1 = min(max(y1, 0), HH - 1);

    const float x0f = (float)x0, x1f = (float)x1;
    const float y0f = (float)y0, y1f = (float)y1;
    const float wA = (x1f - x) * (y1f - y);
    const float wB = (x1f - x) * (y - y0f);
    const float wC = (x - x0f) * (y1f - y);
    const float wD = (x - x0f) * (y - y0f);

    const float4* __restrict__ img4 = (const float4*)image;
    // float4 index of pixel (b, yy, xx), channel quad c4
    const long long batch_base = (long long)b * (HH * WW * (CC / 4));
    const int rowA = (y0 * WW + x0) * (CC / 4) + c4;
    const int rowB = (y1 * WW + x0) * (CC / 4) + c4;
    const int rowC = (y0 * WW + x1) * (CC / 4) + c4;
    const int rowD = (y1 * WW + x1) * (CC / 4) + c4;

    const float4 pA = img4[batch_base + rowA];
    const float4 pB = img4[batch_base + rowB];
    const float4 pC = img4[batch_base + rowC];
    const float4 pD = img4[batch_base + rowD];

    float4 o;
    o.x = pA.x * wA + pB.x * wB + pC.x * wC + pD.x * wD;
    o.y = pA.y * wA + pB.y * wB + pC.y * wC + pD.y * wD;
    o.z = pA.z * wA + pB.z * wB + pC.z * wC + pD.z * wD;
    o.w = pA.w * wA + pB.w * wB + pC.w * wC + pD.w * wD;

    ((float4*)out)[gid] = o;
}

extern "C" void kernel_launch(void* const* d_in, const int* in_sizes, int n_in,
                              void* d_out, int out_size, void* d_ws, size_t ws_size,
                              hipStream_t stream) {
    const float* image = (const float*)d_in[0];
    const float* theta = (const float*)d_in[1];
    float* out = (float*)d_out;

    const int total4 = BB * OUT_H * OUT_W * (CC / 4);  // 4,194,304
    const int block = 256;
    const int grid = total4 / block;                   // 16,384
    bilin_kernel<<<grid, block, 0, stream>>>(image, theta, out);
}